// Round 13
// baseline (636.108 us; speedup 1.0000x reference)
//
#include <hip/hip_runtime.h>

typedef unsigned int uint;
typedef unsigned short ushort;
typedef __attribute__((ext_vector_type(8))) short short8;
typedef __attribute__((ext_vector_type(4))) float f32x4;
typedef __attribute__((ext_vector_type(2))) float f32x2;

#define D 128

__device__ __forceinline__ float bf2f(ushort h){ return __uint_as_float(((uint)h)<<16); }
__device__ __forceinline__ ushort f2bf(float f){
  uint u = __float_as_uint(f);
  u += 0x7fff + ((u >> 16) & 1);   // RNE
  return (ushort)(u >> 16);
}
__device__ __forceinline__ float ldf(const void* p, long i, int bf){
  return bf ? bf2f(((const ushort*)p)[i]) : ((const float*)p)[i];
}
__device__ __forceinline__ int imin(int a, int b){ return a < b ? a : b; }

// ---------------- dtype detection ----------------
__global__ __launch_bounds__(256) void detect_kernel(const uint* __restrict__ xw,
                                                     int* __restrict__ flag){
  __shared__ int cnt;
  if (threadIdx.x == 0) cnt = 0;
  __syncthreads();
  uint w = xw[threadIdx.x];
  int ef = (int)((w >> 7) & 0xffu);
  if (ef >= 90 && ef <= 142) atomicAdd(&cnt, 1);
  __syncthreads();
  if (threadIdx.x == 0) flag[0] = (cnt >= 128) ? 1 : 0;
}

// ---------------- CSR build (dst/src are layer-invariant) ----------------
__global__ __launch_bounds__(256) void hist_kernel(const int* __restrict__ dst,
                                                   int* __restrict__ deg, int E_){
  int e = blockIdx.x*256 + threadIdx.x;
  if (e < E_) atomicAdd(&deg[dst[e]], 1);
}

__global__ __launch_bounds__(256) void scan1_kernel(const int* __restrict__ deg,
                                                    int* __restrict__ rs,
                                                    int* __restrict__ bsum, int Nn){
  __shared__ int s[256];
  int tid = threadIdx.x;
  int base = blockIdx.x*512;
  int i0 = base + 2*tid, i1 = i0 + 1;
  int a = (i0 < Nn) ? deg[i0] : 0;
  int b = (i1 < Nn) ? deg[i1] : 0;
  int p = a + b;
  s[tid] = p; __syncthreads();
  for (int off = 1; off < 256; off <<= 1){
    int t = (tid >= off) ? s[tid-off] : 0;
    __syncthreads();
    s[tid] += t;
    __syncthreads();
  }
  int ex = s[tid] - p;
  if (i0 < Nn) rs[i0] = ex;
  if (i1 < Nn) rs[i1] = ex + a;
  if (tid == 255) bsum[blockIdx.x] = s[255];
}

__global__ __launch_bounds__(256) void scan2_kernel(const int* __restrict__ bsum,
                                                    int* __restrict__ boff, int NB){
  __shared__ int s[256];
  int tid = threadIdx.x;
  int v = (tid < NB) ? bsum[tid] : 0;
  s[tid] = v; __syncthreads();
  for (int off = 1; off < 256; off <<= 1){
    int t = (tid >= off) ? s[tid-off] : 0;
    __syncthreads();
    s[tid] += t;
    __syncthreads();
  }
  boff[tid] = s[tid] - v;
}

__global__ __launch_bounds__(256) void scan3_kernel(int* __restrict__ rs,
                                                    const int* __restrict__ boff,
                                                    int* __restrict__ cursor,
                                                    int Nn, int E_){
  int i = blockIdx.x*256 + threadIdx.x;
  if (i < Nn){
    int v = rs[i] + boff[i >> 9];
    rs[i] = v;
    cursor[i] = v;
  }
  if (i == 0) rs[Nn] = E_;
}

__global__ __launch_bounds__(256) void scatter_kernel(const int* __restrict__ dst,
                                                      const int* __restrict__ src,
                                                      int* __restrict__ cursor,
                                                      int2* __restrict__ spp, int E_){
  int e = blockIdx.x*256 + threadIdx.x;
  if (e < E_){
    int pos = atomicAdd(&cursor[dst[e]], 1);
    spp[pos] = make_int2(src[e], e);
  }
}

// CSR-order repack: sarr[ii]=src, paHi[ii][16] = bf16(attr[perm[ii]])
__global__ __launch_bounds__(256) void pack_kernel(const int2* __restrict__ spp,
                                                   const void* __restrict__ eattr,
                                                   ushort* __restrict__ paHi,
                                                   int* __restrict__ sarr,
                                                   int E_, const int* __restrict__ flag){
  int bf = flag[0];
  int ii = blockIdx.x*256 + threadIdx.x;
  if (ii >= E_) return;
  int2 p = spp[ii];
  sarr[ii] = p.x;
  if (bf){
    const ushort* ea = (const ushort*)eattr + (long)p.y*16;
    *(uint4*)(paHi + (long)ii*16)     = *(const uint4*)(ea);
    *(uint4*)(paHi + (long)ii*16 + 8) = *(const uint4*)(ea + 8);
    return;
  }
  ushort hv[16];
  #pragma unroll
  for (int k = 0; k < 16; k++)
    hv[k] = f2bf(((const float*)eattr)[(long)p.y*16 + k]);
  *(uint4*)(paHi + (long)ii*16)     = *(uint4*)&hv[0];
  *(uint4*)(paHi + (long)ii*16 + 8) = *(uint4*)&hv[8];
}

// ---------------- MLP W transpose, hi bf16 only ----------------
__global__ __launch_bounds__(256) void trans_kernel(const void* __restrict__ W,
                                                    ushort* __restrict__ hi,
                                                    const int* __restrict__ flag){
  int bf = flag[0];
  int idx = blockIdx.x*256 + threadIdx.x;   // grid covers 3*16384 exactly
  int l = idx >> 14, rem = idx & 16383, k = rem >> 7, n = rem & 127;
  float w = ldf(W, idx, bf);
  int di = (l << 14) | (n << 7) | k;
  hi[di] = f2bf(w);
}

// edge-W transpose: in ew[l][k(16)][n(128)] -> out [l][n][k(16)] hi bf16
__global__ __launch_bounds__(256) void trans_edge_kernel(const void* __restrict__ W,
                                                         ushort* __restrict__ hi,
                                                         const int* __restrict__ flag){
  int bf = flag[0];
  int idx = blockIdx.x*256 + threadIdx.x;   // grid covers 3*2048 exactly
  int l = idx >> 11, rem = idx & 2047, k = rem >> 7, n = rem & 127;
  float w = ldf(W, idx, bf);
  int di = (l << 11) | (n << 4) | k;
  hi[di] = f2bf(w);
}

// ---------------- edge gather-aggregate + PRE combine ----------------
// hpre[n] = (1+eps)*(x[n]+vn) + sum_{e:dst=n} relu(x[src]+vn + attr@W + b)
//
// r13 (= r12 with the mlp staging copy-width bug fixed): all inter-stage
// activations bf16 — x gathers read 256B rows (gather demand 307->154MB,
// working set 12.8MB -> better L2/L3 residency), hpre stored packed bf16.
template<bool FIRST>
__global__ __launch_bounds__(256, 8) void edge_agg_kernel(
    const int* __restrict__ sarr, const int* __restrict__ rs,
    const ushort* __restrict__ paHi,                                   // [E][16] CSR order
    const ushort* __restrict__ weHi,                                   // [128][16] this layer
    const void* __restrict__ eb, const void* __restrict__ vn,
    const void* __restrict__ epsp, int layer,
    const void* __restrict__ xin, const ushort* __restrict__ xws,
    ushort* __restrict__ hpre, int Nn, const int* __restrict__ flag)
{
  int bf = flag[0];
  __shared__ float eemb[4][16][132];      // per-wave scratch
  int lane = threadIdx.x & 63, wvi = threadIdx.x >> 6;
  int m_ = lane & 15, q = lane >> 4;      // MFMA coords
  int d0 = lane << 1;
  const ushort* wrow = weHi + m_*16 + (q&1)*8;   // + ci*256 per fragment (L1-hot)
  f32x2 vn2, cv;
  vn2[0] = ldf(vn, (long)layer*128 + d0,     bf);
  vn2[1] = ldf(vn, (long)layer*128 + d0 + 1, bf);
  cv[0] = ldf(eb, (long)layer*128 + d0,     bf) + vn2[0];
  cv[1] = ldf(eb, (long)layer*128 + d0 + 1, bf) + vn2[1];
  float epsv = 1.f + ldf(epsp, layer, bf);
  const float*  xf = (const float*)xin;                        // FIRST && !bf
  const ushort* xh = FIRST ? (const ushort*)xin : xws;         // bf16 rows

  for (int n0 = (blockIdx.x*4 + wvi)*2; n0 < Nn; n0 += gridDim.x*8){
    int beg   = rs[n0];
    int split = rs[n0+1];
    int end   = (n0+2 <= Nn) ? rs[n0+2] : split;
    f32x2 accA = {0.f, 0.f}, accB = {0.f, 0.f};
    int scur = (beg < end) ? sarr[imin(beg + m_, end - 1)] : 0;

    for (int ii = beg; ii < end; ii += 16){
      // ---- A-frag: attr-hi K-rows (q<2); q>=2 rows are zero
      short8 afrag = {0,0,0,0,0,0,0,0};
      if (q < 2)
        afrag = *(const short8*)(paHi + (long)imin(ii + m_, end - 1)*16 + (q&1)*8);
      // ---- prefetch next chunk's src
      bool more = (ii + 16) < end;
      int snext = more ? sarr[imin(ii + 16 + m_, end - 1)] : scur;
      // ---- e_emb via MFMA (B-frag streamed from L1), C -> wave LDS
      #pragma unroll
      for (int ci = 0; ci < 8; ci++){
        short8 bfr = *(const short8*)(wrow + ci*256);
        f32x4 acc = {0.f,0.f,0.f,0.f};
        acc = __builtin_amdgcn_mfma_f32_16x16x32_bf16(afrag, bfr, acc, 0, 0, 0);
        int c = ci*16 + m_;
        #pragma unroll
        for (int rg = 0; rg < 4; rg++) eemb[wvi][q*4+rg][c] = acc[rg];
      }
      // ---- combine in 8-edge batches: issue gathers first, then reduce
      #pragma unroll
      for (int jb = 0; jb < 2; jb++){
        int ss[8];
        #pragma unroll
        for (int j = 0; j < 8; j++) ss[j] = __shfl(scur, jb*8 + j);
        f32x2 xv[8];
        #pragma unroll
        for (int j = 0; j < 8; j++){
          if (!FIRST || bf){
            uint u = *(const uint*)(xh + (long)ss[j]*D + d0);
            xv[j][0] = __uint_as_float(u << 16);
            xv[j][1] = __uint_as_float(u & 0xffff0000u);
          } else {
            xv[j] = *(const f32x2*)(xf + (long)ss[j]*D + d0);
          }
        }
        #pragma unroll
        for (int j = 0; j < 8; j++){
          int gidx = ii + jb*8 + j;
          f32x2 ee = *(const f32x2*)&eemb[wvi][jb*8 + j][d0];
          float r0 = fmaxf(cv[0] + xv[j][0] + ee[0], 0.f);
          float r1 = fmaxf(cv[1] + xv[j][1] + ee[1], 0.f);
          bool inA = gidx < split;
          bool inB = (!inA) && (gidx < end);
          accA[0] += inA ? r0 : 0.f;  accA[1] += inA ? r1 : 0.f;
          accB[0] += inB ? r0 : 0.f;  accB[1] += inB ? r1 : 0.f;
        }
      }
      scur = snext;
    }
    // ---- PRE combine + store both rows (packed bf16)
    f32x2 xn;
    if (!FIRST || bf){
      uint u = *(const uint*)(xh + (long)n0*D + d0);
      xn[0] = __uint_as_float(u << 16);
      xn[1] = __uint_as_float(u & 0xffff0000u);
    } else {
      xn = *(const f32x2*)(xf + (long)n0*D + d0);
    }
    float h0v = epsv*(xn[0] + vn2[0]) + accA[0];
    float h1v = epsv*(xn[1] + vn2[1]) + accA[1];
    *(uint*)(hpre + (long)n0*D + d0) = (uint)f2bf(h0v) | ((uint)f2bf(h1v) << 16);
    if (n0 + 1 < Nn){
      f32x2 xm;
      if (!FIRST || bf){
        uint u = *(const uint*)(xh + (long)(n0+1)*D + d0);
        xm[0] = __uint_as_float(u << 16);
        xm[1] = __uint_as_float(u & 0xffff0000u);
      } else {
        xm = *(const f32x2*)(xf + (long)(n0+1)*D + d0);
      }
      float g0v = epsv*(xm[0] + vn2[0]) + accB[0];
      float g1v = epsv*(xm[1] + vn2[1]) + accB[1];
      *(uint*)(hpre + (long)(n0+1)*D + d0) = (uint)f2bf(g0v) | ((uint)f2bf(g1v) << 16);
    }
  }
}

// ---------------- fused node MLP + pooling epilogue ----------------
// out = relu(h@W1+b1)@W2+b2; gbuf[batch[r], colOff+c] += out[r][c]
// r13: hpre arrives bf16 -> raw copy staging (32 ushorts = 4 x uint4 per
// thread; r12's bug was copying only 2). outp written bf16.
__global__ __launch_bounds__(256) void mlp_fused(
    const ushort* __restrict__ hpre,
    const ushort* __restrict__ w1hi, const ushort* __restrict__ w2hi,
    const void* __restrict__ b1v, const void* __restrict__ b2v, int layer,
    ushort* __restrict__ outp, int Nn, const int* __restrict__ flag,
    const int* __restrict__ batch, float* __restrict__ gbuf, int colOff)
{
  int bf = flag[0];
  __shared__ ushort sbuf[64][136];      // bf16 h plane; reused for packed h1
  __shared__ float bias1[D], bias2[D];
  __shared__ int bseg[64];
  __shared__ float gpart[8][132];
  int tid = threadIdx.x;
  if (tid < D){
    bias1[tid] = ldf(b1v, (long)layer*D + tid, bf);
    bias2[tid] = ldf(b2v, (long)layer*D + tid, bf);
  }
  if (tid < 64){
    long rr = (long)blockIdx.x*64 + tid;
    bseg[tid] = batch[(rr < Nn) ? rr : (Nn - 1)];
  }
  for (int i = tid; i < 8*132; i += 256) ((float*)gpart)[i] = 0.f;
  int srow = tid >> 2, scb = (tid & 3) << 5;
  long r = (long)blockIdx.x*64 + srow;
  {
    // raw bf16 copy: 32 ushorts = 4 x uint4 per thread
    if (r < Nn){
      const uint4* xp = (const uint4*)(hpre + r*D + scb);
      *(uint4*)&sbuf[srow][scb]      = xp[0];
      *(uint4*)&sbuf[srow][scb + 8]  = xp[1];
      *(uint4*)&sbuf[srow][scb + 16] = xp[2];
      *(uint4*)&sbuf[srow][scb + 24] = xp[3];
    } else {
      uint4 z = {0,0,0,0};
      *(uint4*)&sbuf[srow][scb]      = z;
      *(uint4*)&sbuf[srow][scb + 8]  = z;
      *(uint4*)&sbuf[srow][scb + 16] = z;
      *(uint4*)&sbuf[srow][scb + 24] = z;
    }
  }
  __syncthreads();

  int bmin = bseg[0], bmax = bseg[63];
  int nseg = bmax - bmin + 1;
  bool useL = (nseg <= 8);

  int lane = tid & 63, wvi = tid >> 6;
  int m = lane & 15, kq = lane >> 4;
  int lr = wvi*16 + m;
  short8 aHi[4];
  #pragma unroll
  for (int ki = 0; ki < 4; ki++)
    aHi[ki] = *(const short8*)&sbuf[lr][ki*32 + kq*8];
  float h1[8][4];
  #pragma unroll
  for (int ci = 0; ci < 8; ci++){
    int c = ci*16 + m;
    f32x4 acc;
    float bv = bias1[c];
    acc[0] = bv; acc[1] = bv; acc[2] = bv; acc[3] = bv;
    const ushort* bp = w1hi + ((long)c << 7) + kq*8;
    #pragma unroll
    for (int ki = 0; ki < 4; ki++){
      short8 bfr = *(const short8*)(bp + ki*32);
      acc = __builtin_amdgcn_mfma_f32_16x16x32_bf16(aHi[ki], bfr, acc, 0, 0, 0);
    }
    #pragma unroll
    for (int rg = 0; rg < 4; rg++) h1[ci][rg] = fmaxf(acc[rg], 0.f);
  }
  __syncthreads();
  // repack h1 (bf16, single plane) into sbuf
  #pragma unroll
  for (int ci = 0; ci < 8; ci++){
    int c = ci*16 + m;
    #pragma unroll
    for (int rg = 0; rg < 4; rg++){
      int rl = wvi*16 + kq*4 + rg;
      sbuf[rl][c] = f2bf(h1[ci][rg]);
    }
  }
  __syncthreads();
  #pragma unroll
  for (int ki = 0; ki < 4; ki++)
    aHi[ki] = *(const short8*)&sbuf[lr][ki*32 + kq*8];
  int rl0 = wvi*16 + kq*4;
  long rowBase = (long)blockIdx.x*64 + rl0;
  int s0 = bseg[rl0], s3 = bseg[rl0+3];
  #pragma unroll
  for (int ci = 0; ci < 8; ci++){
    int c = ci*16 + m;
    f32x4 acc;
    float bv = bias2[c];
    acc[0] = bv; acc[1] = bv; acc[2] = bv; acc[3] = bv;
    const ushort* bp = w2hi + ((long)c << 7) + kq*8;
    #pragma unroll
    for (int ki = 0; ki < 4; ki++){
      short8 bfr = *(const short8*)(bp + ki*32);
      acc = __builtin_amdgcn_mfma_f32_16x16x32_bf16(aHi[ki], bfr, acc, 0, 0, 0);
    }
    #pragma unroll
    for (int rg = 0; rg < 4; rg++){
      long orow = rowBase + rg;
      if (orow < Nn) outp[orow*D + c] = f2bf(acc[rg]);
    }
    // ---- pooling contribution (fp32, from the accumulator directly)
    if (useL){
      if (s0 == s3 && rowBase + 3 < Nn){
        atomicAdd(&gpart[s0 - bmin][c], acc[0] + acc[1] + acc[2] + acc[3]);
      } else {
        #pragma unroll
        for (int rg = 0; rg < 4; rg++){
          if (rowBase + rg < Nn)
            atomicAdd(&gpart[bseg[rl0+rg] - bmin][c], acc[rg]);
        }
      }
    } else {
      #pragma unroll
      for (int rg = 0; rg < 4; rg++){
        if (rowBase + rg < Nn)
          unsafeAtomicAdd(&gbuf[(long)bseg[rl0+rg]*384 + colOff + c], acc[rg]);
      }
    }
  }
  if (useL){
    __syncthreads();
    if (tid < 128){
      for (int s = 0; s < nseg; s++){
        float v = gpart[s][tid];
        if (v != 0.f)
          unsafeAtomicAdd(&gbuf[(long)(bmin + s)*384 + colOff + tid], v);
      }
    }
  }
}

// ---------------- head: Linear->LN->ReLU x2 -> Linear ----------------
// Split-k, 1024 threads/graph (r9: head dropped out of top-5)
__global__ __launch_bounds__(1024) void head_kernel(
    const float* __restrict__ g,
    const void* __restrict__ w1, const void* __restrict__ b1,
    const void* __restrict__ g1, const void* __restrict__ be1,
    const void* __restrict__ w2, const void* __restrict__ b2,
    const void* __restrict__ g2, const void* __restrict__ be2,
    const void* __restrict__ ow, const void* __restrict__ ob,
    void* __restrict__ outp, const int* __restrict__ flag)
{
  int bf = flag[0];
  __shared__ float grow[384];
  __shared__ float part[1024];      // [4][256] for GEMM1, [8][128] for GEMM2
  __shared__ float h1[256];
  __shared__ float h2[128];
  __shared__ float redA[4], redB[4], stats[2];
  int b = blockIdx.x, tid = threadIdx.x;
  for (int i = tid; i < 384; i += 1024) grow[i] = g[(long)b*384 + i];
  __syncthreads();
  // GEMM1: col = tid&255, sec = tid>>8 -> k in [96*sec, 96*sec+96)
  {
    int col = tid & 255, sec = tid >> 8;
    int k0 = sec * 96;
    float v = 0.f;
    for (int k = k0; k < k0 + 96; k++)
      v += grow[k] * ldf(w1, (long)k*256 + col, bf);
    part[sec*256 + col] = v;
  }
  __syncthreads();
  float v1 = 0.f;
  if (tid < 256){
    v1 = part[tid] + part[256+tid] + part[512+tid] + part[768+tid]
       + ldf(b1, tid, bf);
    float s = v1, s2 = v1*v1;
    for (int o = 32; o; o >>= 1){ s += __shfl_down(s,o); s2 += __shfl_down(s2,o); }
    if ((tid & 63) == 0){ redA[tid>>6] = s; redB[tid>>6] = s2; }
  }
  __syncthreads();
  if (tid == 0){
    float S = redA[0]+redA[1]+redA[2]+redA[3];
    float S2 = redB[0]+redB[1]+redB[2]+redB[3];
    float mu = S / 256.f;
    stats[0] = mu; stats[1] = rsqrtf(S2/256.f - mu*mu + 1e-5f);
  }
  __syncthreads();
  if (tid < 256){
    float y = (v1 - stats[0]) * stats[1] * ldf(g1, tid, bf) + ldf(be1, tid, bf);
    h1[tid] = fmaxf(y, 0.f);
  }
  __syncthreads();
  // GEMM2: col = tid&127, sec = tid>>7 -> k in [32*sec, 32*sec+32)
  {
    int col = tid & 127, sec = tid >> 7;
    int k0 = sec * 32;
    float v = 0.f;
    for (int k = k0; k < k0 + 32; k++)
      v += h1[k] * ldf(w2, (long)k*128 + col, bf);
    part[sec*128 + col] = v;
  }
  __syncthreads();
  float v2 = 0.f;
  if (tid < 128){
    v2 = ldf(b2, tid, bf);
    #pragma unroll
    for (int s = 0; s < 8; s++) v2 += part[s*128 + tid];
    float s = v2, s2 = v2*v2;
    for (int o = 32; o; o >>= 1){ s += __shfl_down(s,o); s2 += __shfl_down(s2,o); }
    if ((tid & 63) == 0){ redA[tid>>6] = s; redB[tid>>6] = s2; }
  }
  __syncthreads();
  if (tid == 0){
    float S = redA[0]+redA[1];
    float S2 = redB[0]+redB[1];
    float mu = S / 128.f;
    stats[0] = mu; stats[1] = rsqrtf(S2/128.f - mu*mu + 1e-5f);
  }
  __syncthreads();
  if (tid < 128){
    float y2 = (v2 - stats[0]) * stats[1] * ldf(g2, tid, bf) + ldf(be2, tid, bf);
    h2[tid] = fmaxf(y2, 0.f);
  }
  __syncthreads();
  if (tid < 128){
    float p = h2[tid] * ldf(ow, tid, bf);
    float s = p;
    for (int o = 32; o; o >>= 1) s += __shfl_down(s, o);
    if ((tid & 63) == 0) redA[tid>>6] = s;
  }
  __syncthreads();
  if (tid == 0){
    float r = redA[0]+redA[1] + ldf(ob, 0, bf);
    if (bf) ((ushort*)outp)[b] = f2bf(r);
    else    ((float*)outp)[b]  = r;
  }
}

extern "C" void kernel_launch(void* const* d_in, const int* in_sizes, int n_in,
                              void* d_out, int out_size, void* d_ws, size_t ws_size,
                              hipStream_t stream)
{
  const void* x_in  = d_in[0];
  const int*  eidx  = (const int*)d_in[1];
  const void* eattr = d_in[2];
  const int*  batch = (const int*)d_in[3];
  const void* vn    = d_in[4];
  const void* ew    = d_in[5];
  const void* eb    = d_in[6];
  const void* epsp  = d_in[7];
  const void* w1p   = d_in[8];
  const void* b1p   = d_in[9];
  const void* w2p   = d_in[10];
  const void* b2p   = d_in[11];
  const void* lw1   = d_in[12];
  const void* lb1   = d_in[13];
  const void* ln1g  = d_in[14];
  const void* ln1b  = d_in[15];
  const void* lw2   = d_in[16];
  const void* lb2   = d_in[17];
  const void* ln2g  = d_in[18];
  const void* ln2b  = d_in[19];
  const void* owp   = d_in[20];
  const void* obp   = d_in[21];

  int Nn = in_sizes[0] / D;     // 50000
  int Ee = in_sizes[1] / 2;     // 600000
  int Gg = out_size;            // 512
  const int* srcp = eidx;
  const int* dstp = eidx + Ee;

  ushort* A     = (ushort*)d_ws;                // hpre scratch (bf16)
  ushort* B     = A + (size_t)Nn*D;             // layer in/out ping-pong (bf16)
  float*  gbuf  = (float*)(B + (size_t)Nn*D);
  ushort* wT1hi = (ushort*)(gbuf + (size_t)Gg*384);
  ushort* wT2hi = wT1hi + 3*D*D;
  ushort* weHi  = wT2hi + 3*D*D;      // [3][128][16]
  int*    flag  = (int*)(weHi + 3*128*16);
  int*    deg     = flag + 1;
  int*    rs      = deg + Nn;        // N+1
  int*    cursor  = rs + Nn + 1;
  int*    bsum    = cursor + Nn;
  int*    boff    = bsum + 256;
  int2*   spp     = (int2*)(boff + 256);          // [E]
  int*    sarr    = (int*)(spp + Ee);             // [E]
  ushort* paHi    = (ushort*)(sarr + Ee);         // [E][16]

  detect_kernel<<<1,256,0,stream>>>((const uint*)x_in, flag);

  // CSR build (once; dst/src invariant across layers)
  int NB = (Nn + 511) / 512;
  hipMemsetAsync(deg, 0, (size_t)Nn*sizeof(int), stream);
  hipMemsetAsync(gbuf, 0, (size_t)Gg*384*sizeof(float), stream);
  hist_kernel<<<(Ee+255)/256,256,0,stream>>>(dstp, deg, Ee);
  scan1_kernel<<<NB,256,0,stream>>>(deg, rs, bsum, Nn);
  scan2_kernel<<<1,256,0,stream>>>(bsum, boff, NB);
  scan3_kernel<<<(Nn+255)/256,256,0,stream>>>(rs, boff, cursor, Nn, Ee);
  scatter_kernel<<<(Ee+255)/256,256,0,stream>>>(dstp, srcp, cursor, spp, Ee);
  pack_kernel<<<(Ee+255)/256,256,0,stream>>>(spp, eattr, paHi, sarr, Ee, flag);

  trans_kernel<<<192,256,0,stream>>>(w1p, wT1hi, flag);
  trans_kernel<<<192,256,0,stream>>>(w2p, wT2hi, flag);
  trans_edge_kernel<<<24,256,0,stream>>>(ew, weHi, flag);

  int mlpGrid  = (Nn + 63) / 64;    // 782
  int edgeGrid = 2048;              // grid-stride, ~3 node-pairs per wave
  for (int i = 0; i < 3; i++){
    if (i == 0)
      edge_agg_kernel<true ><<<edgeGrid,256,0,stream>>>(sarr, rs, paHi,
                                                        weHi + (size_t)i*2048,
                                                        eb, vn, epsp, i, x_in, nullptr, A, Nn, flag);
    else
      edge_agg_kernel<false><<<edgeGrid,256,0,stream>>>(sarr, rs, paHi,
                                                        weHi + (size_t)i*2048,
                                                        eb, vn, epsp, i, nullptr, B, A, Nn, flag);
    // MLP (+ fused pooling): reads A (bf16), writes B (bf16, next-layer x)
    mlp_fused<<<mlpGrid,256,0,stream>>>(A,
                                        wT1hi + (size_t)i*D*D, wT2hi + (size_t)i*D*D,
                                        b1p, b2p, i, B, Nn, flag, batch, gbuf, i*D);
  }
  head_kernel<<<Gg,1024,0,stream>>>(gbuf, lw1, lb1, ln1g, ln1b,
                                    lw2, lb2, ln2g, ln2b, owp, obp, d_out, flag);
}

// Round 15
// 540.597 us; speedup vs baseline: 1.1767x; 1.1767x over previous
//
#include <hip/hip_runtime.h>

typedef unsigned int uint;
typedef unsigned short ushort;
typedef __attribute__((ext_vector_type(8))) short short8;
typedef __attribute__((ext_vector_type(4))) float f32x4;
typedef __attribute__((ext_vector_type(2))) float f32x2;

#define D 128

__device__ __forceinline__ float bf2f(ushort h){ return __uint_as_float(((uint)h)<<16); }
__device__ __forceinline__ ushort f2bf(float f){
  uint u = __float_as_uint(f);
  u += 0x7fff + ((u >> 16) & 1);   // RNE
  return (ushort)(u >> 16);
}
__device__ __forceinline__ float ldf(const void* p, long i, int bf){
  return bf ? bf2f(((const ushort*)p)[i]) : ((const float*)p)[i];
}
__device__ __forceinline__ int imin(int a, int b){ return a < b ? a : b; }

// ---------------- dtype detection ----------------
__global__ __launch_bounds__(256) void detect_kernel(const uint* __restrict__ xw,
                                                     int* __restrict__ flag){
  __shared__ int cnt;
  if (threadIdx.x == 0) cnt = 0;
  __syncthreads();
  uint w = xw[threadIdx.x];
  int ef = (int)((w >> 7) & 0xffu);
  if (ef >= 90 && ef <= 142) atomicAdd(&cnt, 1);
  __syncthreads();
  if (threadIdx.x == 0) flag[0] = (cnt >= 128) ? 1 : 0;
}

// ---------------- CSR build (dst/src are layer-invariant) ----------------
__global__ __launch_bounds__(256) void hist_kernel(const int* __restrict__ dst,
                                                   int* __restrict__ deg, int E_){
  int e = blockIdx.x*256 + threadIdx.x;
  if (e < E_) atomicAdd(&deg[dst[e]], 1);
}

__global__ __launch_bounds__(256) void scan1_kernel(const int* __restrict__ deg,
                                                    int* __restrict__ rs,
                                                    int* __restrict__ bsum, int Nn){
  __shared__ int s[256];
  int tid = threadIdx.x;
  int base = blockIdx.x*512;
  int i0 = base + 2*tid, i1 = i0 + 1;
  int a = (i0 < Nn) ? deg[i0] : 0;
  int b = (i1 < Nn) ? deg[i1] : 0;
  int p = a + b;
  s[tid] = p; __syncthreads();
  for (int off = 1; off < 256; off <<= 1){
    int t = (tid >= off) ? s[tid-off] : 0;
    __syncthreads();
    s[tid] += t;
    __syncthreads();
  }
  int ex = s[tid] - p;
  if (i0 < Nn) rs[i0] = ex;
  if (i1 < Nn) rs[i1] = ex + a;
  if (tid == 255) bsum[blockIdx.x] = s[255];
}

__global__ __launch_bounds__(256) void scan2_kernel(const int* __restrict__ bsum,
                                                    int* __restrict__ boff, int NB){
  __shared__ int s[256];
  int tid = threadIdx.x;
  int v = (tid < NB) ? bsum[tid] : 0;
  s[tid] = v; __syncthreads();
  for (int off = 1; off < 256; off <<= 1){
    int t = (tid >= off) ? s[tid-off] : 0;
    __syncthreads();
    s[tid] += t;
    __syncthreads();
  }
  boff[tid] = s[tid] - v;
}

__global__ __launch_bounds__(256) void scan3_kernel(int* __restrict__ rs,
                                                    const int* __restrict__ boff,
                                                    int* __restrict__ cursor,
                                                    int Nn, int E_){
  int i = blockIdx.x*256 + threadIdx.x;
  if (i < Nn){
    int v = rs[i] + boff[i >> 9];
    rs[i] = v;
    cursor[i] = v;
  }
  if (i == 0) rs[Nn] = E_;
}

__global__ __launch_bounds__(256) void scatter_kernel(const int* __restrict__ dst,
                                                      const int* __restrict__ src,
                                                      int* __restrict__ cursor,
                                                      int2* __restrict__ spp, int E_){
  int e = blockIdx.x*256 + threadIdx.x;
  if (e < E_){
    int pos = atomicAdd(&cursor[dst[e]], 1);
    spp[pos] = make_int2(src[e], e);
  }
}

// CSR-order repack: sarr[ii]=src, paHi[ii][16] = bf16(attr[perm[ii]])
__global__ __launch_bounds__(256) void pack_kernel(const int2* __restrict__ spp,
                                                   const void* __restrict__ eattr,
                                                   ushort* __restrict__ paHi,
                                                   int* __restrict__ sarr,
                                                   int E_, const int* __restrict__ flag){
  int bf = flag[0];
  int ii = blockIdx.x*256 + threadIdx.x;
  if (ii >= E_) return;
  int2 p = spp[ii];
  sarr[ii] = p.x;
  if (bf){
    const ushort* ea = (const ushort*)eattr + (long)p.y*16;
    *(uint4*)(paHi + (long)ii*16)     = *(const uint4*)(ea);
    *(uint4*)(paHi + (long)ii*16 + 8) = *(const uint4*)(ea + 8);
    return;
  }
  ushort hv[16];
  #pragma unroll
  for (int k = 0; k < 16; k++)
    hv[k] = f2bf(((const float*)eattr)[(long)p.y*16 + k]);
  *(uint4*)(paHi + (long)ii*16)     = *(uint4*)&hv[0];
  *(uint4*)(paHi + (long)ii*16 + 8) = *(uint4*)&hv[8];
}

// ---------------- MLP W transpose, hi bf16 only ----------------
__global__ __launch_bounds__(256) void trans_kernel(const void* __restrict__ W,
                                                    ushort* __restrict__ hi,
                                                    const int* __restrict__ flag){
  int bf = flag[0];
  int idx = blockIdx.x*256 + threadIdx.x;   // grid covers 3*16384 exactly
  int l = idx >> 14, rem = idx & 16383, k = rem >> 7, n = rem & 127;
  float w = ldf(W, idx, bf);
  int di = (l << 14) | (n << 7) | k;
  hi[di] = f2bf(w);
}

// edge-W transpose: in ew[l][k(16)][n(128)] -> out [l][n][k(16)] hi bf16
__global__ __launch_bounds__(256) void trans_edge_kernel(const void* __restrict__ W,
                                                         ushort* __restrict__ hi,
                                                         const int* __restrict__ flag){
  int bf = flag[0];
  int idx = blockIdx.x*256 + threadIdx.x;   // grid covers 3*2048 exactly
  int l = idx >> 11, rem = idx & 2047, k = rem >> 7, n = rem & 127;
  float w = ldf(W, idx, bf);
  int di = (l << 11) | (n << 4) | k;
  hi[di] = f2bf(w);
}

// ---------------- edge gather-aggregate + PRE combine ----------------
// hpre[n] = (1+eps)*(x[n]+vn) + sum_{e:dst=n} relu(x[src]+vn + attr@W + b)
//
// r14 = r13 (bf16 activations, halved gather traffic: FETCH 153->74MB) +
// the r4-proven sched_barrier fence after each 8-gather batch. r13's
// regression signature (VGPR 68->56, dur +35%) matched r3: hipcc sank the
// bf16 load->unpack->use chain to the combine, serializing gather latency.
// The fence pins batch-issue; live set is only 8 uints — no occupancy cost.
template<bool FIRST>
__global__ __launch_bounds__(256, 8) void edge_agg_kernel(
    const int* __restrict__ sarr, const int* __restrict__ rs,
    const ushort* __restrict__ paHi,                                   // [E][16] CSR order
    const ushort* __restrict__ weHi,                                   // [128][16] this layer
    const void* __restrict__ eb, const void* __restrict__ vn,
    const void* __restrict__ epsp, int layer,
    const void* __restrict__ xin, const ushort* __restrict__ xws,
    ushort* __restrict__ hpre, int Nn, const int* __restrict__ flag)
{
  int bf = flag[0];
  __shared__ float eemb[4][16][132];      // per-wave scratch
  int lane = threadIdx.x & 63, wvi = threadIdx.x >> 6;
  int m_ = lane & 15, q = lane >> 4;      // MFMA coords
  int d0 = lane << 1;
  const ushort* wrow = weHi + m_*16 + (q&1)*8;   // + ci*256 per fragment (L1-hot)
  f32x2 vn2, cv;
  vn2[0] = ldf(vn, (long)layer*128 + d0,     bf);
  vn2[1] = ldf(vn, (long)layer*128 + d0 + 1, bf);
  cv[0] = ldf(eb, (long)layer*128 + d0,     bf) + vn2[0];
  cv[1] = ldf(eb, (long)layer*128 + d0 + 1, bf) + vn2[1];
  float epsv = 1.f + ldf(epsp, layer, bf);
  const float*  xf = (const float*)xin;                        // FIRST && !bf
  const ushort* xh = FIRST ? (const ushort*)xin : xws;         // bf16 rows

  for (int n0 = (blockIdx.x*4 + wvi)*2; n0 < Nn; n0 += gridDim.x*8){
    int beg   = rs[n0];
    int split = rs[n0+1];
    int end   = (n0+2 <= Nn) ? rs[n0+2] : split;
    f32x2 accA = {0.f, 0.f}, accB = {0.f, 0.f};
    int scur = (beg < end) ? sarr[imin(beg + m_, end - 1)] : 0;

    for (int ii = beg; ii < end; ii += 16){
      // ---- A-frag: attr-hi K-rows (q<2); q>=2 rows are zero
      short8 afrag = {0,0,0,0,0,0,0,0};
      if (q < 2)
        afrag = *(const short8*)(paHi + (long)imin(ii + m_, end - 1)*16 + (q&1)*8);
      // ---- prefetch next chunk's src
      bool more = (ii + 16) < end;
      int snext = more ? sarr[imin(ii + 16 + m_, end - 1)] : scur;
      // ---- e_emb via MFMA (B-frag streamed from L1), C -> wave LDS
      #pragma unroll
      for (int ci = 0; ci < 8; ci++){
        short8 bfr = *(const short8*)(wrow + ci*256);
        f32x4 acc = {0.f,0.f,0.f,0.f};
        acc = __builtin_amdgcn_mfma_f32_16x16x32_bf16(afrag, bfr, acc, 0, 0, 0);
        int c = ci*16 + m_;
        #pragma unroll
        for (int rg = 0; rg < 4; rg++) eemb[wvi][q*4+rg][c] = acc[rg];
      }
      // ---- combine in 8-edge batches: issue all 8 gathers, FENCE, reduce
      #pragma unroll
      for (int jb = 0; jb < 2; jb++){
        int ss[8];
        #pragma unroll
        for (int j = 0; j < 8; j++) ss[j] = __shfl(scur, jb*8 + j);
        uint  uu[8];
        f32x2 xv[8];
        if (!FIRST || bf){
          #pragma unroll
          for (int j = 0; j < 8; j++)
            uu[j] = *(const uint*)(xh + (long)ss[j]*D + d0);
        } else {
          #pragma unroll
          for (int j = 0; j < 8; j++)
            xv[j] = *(const f32x2*)(xf + (long)ss[j]*D + d0);
        }
        __builtin_amdgcn_sched_barrier(0);   // pin batch-issue before combine
        #pragma unroll
        for (int j = 0; j < 8; j++){
          int gidx = ii + jb*8 + j;
          f32x2 xj;
          if (!FIRST || bf){
            xj[0] = __uint_as_float(uu[j] << 16);
            xj[1] = __uint_as_float(uu[j] & 0xffff0000u);
          } else xj = xv[j];
          f32x2 ee = *(const f32x2*)&eemb[wvi][jb*8 + j][d0];
          float r0 = fmaxf(cv[0] + xj[0] + ee[0], 0.f);
          float r1 = fmaxf(cv[1] + xj[1] + ee[1], 0.f);
          bool inA = gidx < split;
          bool inB = (!inA) && (gidx < end);
          accA[0] += inA ? r0 : 0.f;  accA[1] += inA ? r1 : 0.f;
          accB[0] += inB ? r0 : 0.f;  accB[1] += inB ? r1 : 0.f;
        }
      }
      scur = snext;
    }
    // ---- PRE combine + store both rows (packed bf16)
    f32x2 xn;
    if (!FIRST || bf){
      uint u = *(const uint*)(xh + (long)n0*D + d0);
      xn[0] = __uint_as_float(u << 16);
      xn[1] = __uint_as_float(u & 0xffff0000u);
    } else {
      xn = *(const f32x2*)(xf + (long)n0*D + d0);
    }
    float h0v = epsv*(xn[0] + vn2[0]) + accA[0];
    float h1v = epsv*(xn[1] + vn2[1]) + accA[1];
    *(uint*)(hpre + (long)n0*D + d0) = (uint)f2bf(h0v) | ((uint)f2bf(h1v) << 16);
    if (n0 + 1 < Nn){
      f32x2 xm;
      if (!FIRST || bf){
        uint u = *(const uint*)(xh + (long)(n0+1)*D + d0);
        xm[0] = __uint_as_float(u << 16);
        xm[1] = __uint_as_float(u & 0xffff0000u);
      } else {
        xm = *(const f32x2*)(xf + (long)(n0+1)*D + d0);
      }
      float g0v = epsv*(xm[0] + vn2[0]) + accB[0];
      float g1v = epsv*(xm[1] + vn2[1]) + accB[1];
      *(uint*)(hpre + (long)(n0+1)*D + d0) = (uint)f2bf(g0v) | ((uint)f2bf(g1v) << 16);
    }
  }
}

// ---------------- fused node MLP + pooling epilogue ----------------
// out = relu(h@W1+b1)@W2+b2; gbuf[batch[r], colOff+c] += out[r][c]
// hpre arrives bf16 -> raw copy staging (32 ushorts = 4 x uint4/thread).
__global__ __launch_bounds__(256) void mlp_fused(
    const ushort* __restrict__ hpre,
    const ushort* __restrict__ w1hi, const ushort* __restrict__ w2hi,
    const void* __restrict__ b1v, const void* __restrict__ b2v, int layer,
    ushort* __restrict__ outp, int Nn, const int* __restrict__ flag,
    const int* __restrict__ batch, float* __restrict__ gbuf, int colOff)
{
  int bf = flag[0];
  __shared__ ushort sbuf[64][136];      // bf16 h plane; reused for packed h1
  __shared__ float bias1[D], bias2[D];
  __shared__ int bseg[64];
  __shared__ float gpart[8][132];
  int tid = threadIdx.x;
  if (tid < D){
    bias1[tid] = ldf(b1v, (long)layer*D + tid, bf);
    bias2[tid] = ldf(b2v, (long)layer*D + tid, bf);
  }
  if (tid < 64){
    long rr = (long)blockIdx.x*64 + tid;
    bseg[tid] = batch[(rr < Nn) ? rr : (Nn - 1)];
  }
  for (int i = tid; i < 8*132; i += 256) ((float*)gpart)[i] = 0.f;
  int srow = tid >> 2, scb = (tid & 3) << 5;
  long r = (long)blockIdx.x*64 + srow;
  {
    if (r < Nn){
      const uint4* xp = (const uint4*)(hpre + r*D + scb);
      *(uint4*)&sbuf[srow][scb]      = xp[0];
      *(uint4*)&sbuf[srow][scb + 8]  = xp[1];
      *(uint4*)&sbuf[srow][scb + 16] = xp[2];
      *(uint4*)&sbuf[srow][scb + 24] = xp[3];
    } else {
      uint4 z = {0,0,0,0};
      *(uint4*)&sbuf[srow][scb]      = z;
      *(uint4*)&sbuf[srow][scb + 8]  = z;
      *(uint4*)&sbuf[srow][scb + 16] = z;
      *(uint4*)&sbuf[srow][scb + 24] = z;
    }
  }
  __syncthreads();

  int bmin = bseg[0], bmax = bseg[63];
  int nseg = bmax - bmin + 1;
  bool useL = (nseg <= 8);

  int lane = tid & 63, wvi = tid >> 6;
  int m = lane & 15, kq = lane >> 4;
  int lr = wvi*16 + m;
  short8 aHi[4];
  #pragma unroll
  for (int ki = 0; ki < 4; ki++)
    aHi[ki] = *(const short8*)&sbuf[lr][ki*32 + kq*8];
  float h1[8][4];
  #pragma unroll
  for (int ci = 0; ci < 8; ci++){
    int c = ci*16 + m;
    f32x4 acc;
    float bv = bias1[c];
    acc[0] = bv; acc[1] = bv; acc[2] = bv; acc[3] = bv;
    const ushort* bp = w1hi + ((long)c << 7) + kq*8;
    #pragma unroll
    for (int ki = 0; ki < 4; ki++){
      short8 bfr = *(const short8*)(bp + ki*32);
      acc = __builtin_amdgcn_mfma_f32_16x16x32_bf16(aHi[ki], bfr, acc, 0, 0, 0);
    }
    #pragma unroll
    for (int rg = 0; rg < 4; rg++) h1[ci][rg] = fmaxf(acc[rg], 0.f);
  }
  __syncthreads();
  // repack h1 (bf16, single plane) into sbuf
  #pragma unroll
  for (int ci = 0; ci < 8; ci++){
    int c = ci*16 + m;
    #pragma unroll
    for (int rg = 0; rg < 4; rg++){
      int rl = wvi*16 + kq*4 + rg;
      sbuf[rl][c] = f2bf(h1[ci][rg]);
    }
  }
  __syncthreads();
  #pragma unroll
  for (int ki = 0; ki < 4; ki++)
    aHi[ki] = *(const short8*)&sbuf[lr][ki*32 + kq*8];
  int rl0 = wvi*16 + kq*4;
  long rowBase = (long)blockIdx.x*64 + rl0;
  int s0 = bseg[rl0], s3 = bseg[rl0+3];
  #pragma unroll
  for (int ci = 0; ci < 8; ci++){
    int c = ci*16 + m;
    f32x4 acc;
    float bv = bias2[c];
    acc[0] = bv; acc[1] = bv; acc[2] = bv; acc[3] = bv;
    const ushort* bp = w2hi + ((long)c << 7) + kq*8;
    #pragma unroll
    for (int ki = 0; ki < 4; ki++){
      short8 bfr = *(const short8*)(bp + ki*32);
      acc = __builtin_amdgcn_mfma_f32_16x16x32_bf16(aHi[ki], bfr, acc, 0, 0, 0);
    }
    #pragma unroll
    for (int rg = 0; rg < 4; rg++){
      long orow = rowBase + rg;
      if (orow < Nn) outp[orow*D + c] = f2bf(acc[rg]);
    }
    // ---- pooling contribution (fp32, from the accumulator directly)
    if (useL){
      if (s0 == s3 && rowBase + 3 < Nn){
        atomicAdd(&gpart[s0 - bmin][c], acc[0] + acc[1] + acc[2] + acc[3]);
      } else {
        #pragma unroll
        for (int rg = 0; rg < 4; rg++){
          if (rowBase + rg < Nn)
            atomicAdd(&gpart[bseg[rl0+rg] - bmin][c], acc[rg]);
        }
      }
    } else {
      #pragma unroll
      for (int rg = 0; rg < 4; rg++){
        if (rowBase + rg < Nn)
          unsafeAtomicAdd(&gbuf[(long)bseg[rl0+rg]*384 + colOff + c], acc[rg]);
      }
    }
  }
  if (useL){
    __syncthreads();
    if (tid < 128){
      for (int s = 0; s < nseg; s++){
        float v = gpart[s][tid];
        if (v != 0.f)
          unsafeAtomicAdd(&gbuf[(long)(bmin + s)*384 + colOff + tid], v);
      }
    }
  }
}

// ---------------- head: Linear->LN->ReLU x2 -> Linear ----------------
// Split-k, 1024 threads/graph (r9: head dropped out of top-5)
__global__ __launch_bounds__(1024) void head_kernel(
    const float* __restrict__ g,
    const void* __restrict__ w1, const void* __restrict__ b1,
    const void* __restrict__ g1, const void* __restrict__ be1,
    const void* __restrict__ w2, const void* __restrict__ b2,
    const void* __restrict__ g2, const void* __restrict__ be2,
    const void* __restrict__ ow, const void* __restrict__ ob,
    void* __restrict__ outp, const int* __restrict__ flag)
{
  int bf = flag[0];
  __shared__ float grow[384];
  __shared__ float part[1024];      // [4][256] for GEMM1, [8][128] for GEMM2
  __shared__ float h1[256];
  __shared__ float h2[128];
  __shared__ float redA[4], redB[4], stats[2];
  int b = blockIdx.x, tid = threadIdx.x;
  for (int i = tid; i < 384; i += 1024) grow[i] = g[(long)b*384 + i];
  __syncthreads();
  // GEMM1: col = tid&255, sec = tid>>8 -> k in [96*sec, 96*sec+96)
  {
    int col = tid & 255, sec = tid >> 8;
    int k0 = sec * 96;
    float v = 0.f;
    for (int k = k0; k < k0 + 96; k++)
      v += grow[k] * ldf(w1, (long)k*256 + col, bf);
    part[sec*256 + col] = v;
  }
  __syncthreads();
  float v1 = 0.f;
  if (tid < 256){
    v1 = part[tid] + part[256+tid] + part[512+tid] + part[768+tid]
       + ldf(b1, tid, bf);
    float s = v1, s2 = v1*v1;
    for (int o = 32; o; o >>= 1){ s += __shfl_down(s,o); s2 += __shfl_down(s2,o); }
    if ((tid & 63) == 0){ redA[tid>>6] = s; redB[tid>>6] = s2; }
  }
  __syncthreads();
  if (tid == 0){
    float S = redA[0]+redA[1]+redA[2]+redA[3];
    float S2 = redB[0]+redB[1]+redB[2]+redB[3];
    float mu = S / 256.f;
    stats[0] = mu; stats[1] = rsqrtf(S2/256.f - mu*mu + 1e-5f);
  }
  __syncthreads();
  if (tid < 256){
    float y = (v1 - stats[0]) * stats[1] * ldf(g1, tid, bf) + ldf(be1, tid, bf);
    h1[tid] = fmaxf(y, 0.f);
  }
  __syncthreads();
  // GEMM2: col = tid&127, sec = tid>>7 -> k in [32*sec, 32*sec+32)
  {
    int col = tid & 127, sec = tid >> 7;
    int k0 = sec * 32;
    float v = 0.f;
    for (int k = k0; k < k0 + 32; k++)
      v += h1[k] * ldf(w2, (long)k*128 + col, bf);
    part[sec*128 + col] = v;
  }
  __syncthreads();
  float v2 = 0.f;
  if (tid < 128){
    v2 = ldf(b2, tid, bf);
    #pragma unroll
    for (int s = 0; s < 8; s++) v2 += part[s*128 + tid];
    float s = v2, s2 = v2*v2;
    for (int o = 32; o; o >>= 1){ s += __shfl_down(s,o); s2 += __shfl_down(s2,o); }
    if ((tid & 63) == 0){ redA[tid>>6] = s; redB[tid>>6] = s2; }
  }
  __syncthreads();
  if (tid == 0){
    float S = redA[0]+redA[1];
    float S2 = redB[0]+redB[1];
    float mu = S / 128.f;
    stats[0] = mu; stats[1] = rsqrtf(S2/128.f - mu*mu + 1e-5f);
  }
  __syncthreads();
  if (tid < 128){
    float y2 = (v2 - stats[0]) * stats[1] * ldf(g2, tid, bf) + ldf(be2, tid, bf);
    h2[tid] = fmaxf(y2, 0.f);
  }
  __syncthreads();
  if (tid < 128){
    float p = h2[tid] * ldf(ow, tid, bf);
    float s = p;
    for (int o = 32; o; o >>= 1) s += __shfl_down(s, o);
    if ((tid & 63) == 0) redA[tid>>6] = s;
  }
  __syncthreads();
  if (tid == 0){
    float r = redA[0]+redA[1] + ldf(ob, 0, bf);
    if (bf) ((ushort*)outp)[b] = f2bf(r);
    else    ((float*)outp)[b]  = r;
  }
}

extern "C" void kernel_launch(void* const* d_in, const int* in_sizes, int n_in,
                              void* d_out, int out_size, void* d_ws, size_t ws_size,
                              hipStream_t stream)
{
  const void* x_in  = d_in[0];
  const int*  eidx  = (const int*)d_in[1];
  const void* eattr = d_in[2];
  const int*  batch = (const int*)d_in[3];
  const void* vn    = d_in[4];
  const void* ew    = d_in[5];
  const void* eb    = d_in[6];
  const void* epsp  = d_in[7];
  const void* w1p   = d_in[8];
  const void* b1p   = d_in[9];
  const void* w2p   = d_in[10];
  const void* b2p   = d_in[11];
  const void* lw1   = d_in[12];
  const void* lb1   = d_in[13];
  const void* ln1g  = d_in[14];
  const void* ln1b  = d_in[15];
  const void* lw2   = d_in[16];
  const void* lb2   = d_in[17];
  const void* ln2g  = d_in[18];
  const void* ln2b  = d_in[19];
  const void* owp   = d_in[20];
  const void* obp   = d_in[21];

  int Nn = in_sizes[0] / D;     // 50000
  int Ee = in_sizes[1] / 2;     // 600000
  int Gg = out_size;            // 512
  const int* srcp = eidx;
  const int* dstp = eidx + Ee;

  ushort* A     = (ushort*)d_ws;                // hpre scratch (bf16)
  ushort* B     = A + (size_t)Nn*D;             // layer in/out ping-pong (bf16)
  float*  gbuf  = (float*)(B + (size_t)Nn*D);
  ushort* wT1hi = (ushort*)(gbuf + (size_t)Gg*384);
  ushort* wT2hi = wT1hi + 3*D*D;
  ushort* weHi  = wT2hi + 3*D*D;      // [3][128][16]
  int*    flag  = (int*)(weHi + 3*128*16);
  int*    deg     = flag + 1;
  int*    rs      = deg + Nn;        // N+1
  int*    cursor  = rs + Nn + 1;
  int*    bsum    = cursor + Nn;
  int*    boff    = bsum + 256;
  int2*   spp     = (int2*)(boff + 256);          // [E]
  int*    sarr    = (int*)(spp + Ee);             // [E]
  ushort* paHi    = (ushort*)(sarr + Ee);         // [E][16]

  detect_kernel<<<1,256,0,stream>>>((const uint*)x_in, flag);

  // CSR build (once; dst/src invariant across layers)
  int NB = (Nn + 511) / 512;
  hipMemsetAsync(deg, 0, (size_t)Nn*sizeof(int), stream);
  hipMemsetAsync(gbuf, 0, (size_t)Gg*384*sizeof(float), stream);
  hist_kernel<<<(Ee+255)/256,256,0,stream>>>(dstp, deg, Ee);
  scan1_kernel<<<NB,256,0,stream>>>(deg, rs, bsum, Nn);
  scan2_kernel<<<1,256,0,stream>>>(bsum, boff, NB);
  scan3_kernel<<<(Nn+255)/256,256,0,stream>>>(rs, boff, cursor, Nn, Ee);
  scatter_kernel<<<(Ee+255)/256,256,0,stream>>>(dstp, srcp, cursor, spp, Ee);
  pack_kernel<<<(Ee+255)/256,256,0,stream>>>(spp, eattr, paHi, sarr, Ee, flag);

  trans_kernel<<<192,256,0,stream>>>(w1p, wT1hi, flag);
  trans_kernel<<<192,256,0,stream>>>(w2p, wT2hi, flag);
  trans_edge_kernel<<<24,256,0,stream>>>(ew, weHi, flag);

  int mlpGrid  = (Nn + 63) / 64;    // 782
  int edgeGrid = 2048;              // grid-stride, ~3 node-pairs per wave
  for (int i = 0; i < 3; i++){
    if (i == 0)
      edge_agg_kernel<true ><<<edgeGrid,256,0,stream>>>(sarr, rs, paHi,
                                                        weHi + (size_t)i*2048,
                                                        eb, vn, epsp, i, x_in, nullptr, A, Nn, flag);
    else
      edge_agg_kernel<false><<<edgeGrid,256,0,stream>>>(sarr, rs, paHi,
                                                        weHi + (size_t)i*2048,
                                                        eb, vn, epsp, i, nullptr, B, A, Nn, flag);
    // MLP (+ fused pooling): reads A (bf16), writes B (bf16, next-layer x)
    mlp_fused<<<mlpGrid,256,0,stream>>>(A,
                                        wT1hi + (size_t)i*D*D, wT2hi + (size_t)i*D*D,
                                        b1p, b2p, i, B, Nn, flag, batch, gbuf, i*D);
  }
  head_kernel<<<Gg,1024,0,stream>>>(gbuf, lw1, lb1, ln1g, ln1b,
                                    lw2, lb2, ln2g, ln2b, owp, obp, d_out, flag);
}